// Round 1
// baseline (269.019 us; speedup 1.0000x reference)
//
#include <hip/hip_runtime.h>
#include <math.h>

#define D_DIM 1024
#define NLEV 8
#define WAVES_PER_BLOCK 4
#define ROWS_PER_WAVE 8

// One wave per row. fp64 internal math so rounding decisions match the fp64
// numpy reference (output is round(3.996*tanh(z)) -- integers; one flipped
// rounding = absmax 1.0 > 0.08 threshold, so fp32 accumulation is not safe).
__global__ __launch_bounds__(256, 2) void fsq_kernel(
    const float* __restrict__ xg,
    const float* __restrict__ gg,
    const float* __restrict__ bg,
    const float* __restrict__ Wg,
    float* __restrict__ outg,
    int nrows)
{
    const int tid  = (int)threadIdx.x;
    const int lane = tid & 63;
    const int wv   = tid >> 6;
    const long wave_global = (long)blockIdx.x * WAVES_PER_BLOCK + wv;
    const long row0 = wave_global * ROWS_PER_WAVE;

    // ---------- startup: V = g*W in fp32 regs; C1_n = sum(g*W), C0_n = sum(b*W) ----------
    // lane owns columns {j*256 + lane*4 .. +3}, j = 0..3  (coalesced float4 loads)
    float4 Vf[NLEV][4];
    double pc1[NLEV], pc0[NLEV];
    #pragma unroll
    for (int n = 0; n < NLEV; ++n) { pc1[n] = 0.0; pc0[n] = 0.0; }

    #pragma unroll
    for (int j = 0; j < 4; ++j) {
        const int col = j * 256 + lane * 4;
        const float4 g4 = *(const float4*)(gg + col);
        const float4 b4 = *(const float4*)(bg + col);
        #pragma unroll
        for (int n = 0; n < NLEV; ++n) {
            const float4 w4 = *(const float4*)(Wg + n * D_DIM + col);
            const double v0 = (double)g4.x * (double)w4.x;
            const double v1 = (double)g4.y * (double)w4.y;
            const double v2 = (double)g4.z * (double)w4.z;
            const double v3 = (double)g4.w * (double)w4.w;
            // with ln_w == ones this fp32 round-trip is exact (V == W bitwise)
            Vf[n][j] = make_float4((float)v0, (float)v1, (float)v2, (float)v3);
            pc1[n] += ((v0 + v1) + (v2 + v3));
            pc0[n] += (((double)b4.x * (double)w4.x + (double)b4.y * (double)w4.y)
                     + ((double)b4.z * (double)w4.z + (double)b4.w * (double)w4.w));
        }
    }
    // wave reduce the 16 constants (once per wave, amortized over 8 rows)
    #pragma unroll
    for (int off = 32; off >= 1; off >>= 1) {
        #pragma unroll
        for (int n = 0; n < NLEV; ++n) {
            pc1[n] += __shfl_xor(pc1[n], off, 64);
            pc0[n] += __shfl_xor(pc0[n], off, 64);
        }
    }
    // lane l keeps only C*(l&7): select tree (avoids dynamic register indexing)
    double su0, su1, su2, su3, sv0, sv1;
    su0 = (lane & 4) ? pc1[4] : pc1[0];
    su1 = (lane & 4) ? pc1[5] : pc1[1];
    su2 = (lane & 4) ? pc1[6] : pc1[2];
    su3 = (lane & 4) ? pc1[7] : pc1[3];
    sv0 = (lane & 2) ? su2 : su0;
    sv1 = (lane & 2) ? su3 : su1;
    const double C1sel = (lane & 1) ? sv1 : sv0;
    su0 = (lane & 4) ? pc0[4] : pc0[0];
    su1 = (lane & 4) ? pc0[5] : pc0[1];
    su2 = (lane & 4) ? pc0[6] : pc0[2];
    su3 = (lane & 4) ? pc0[7] : pc0[3];
    sv0 = (lane & 2) ? su2 : su0;
    sv1 = (lane & 2) ? su3 : su1;
    const double C0sel = (lane & 1) ? sv1 : sv0;

    // ---------- row loop with one-row prefetch ----------
    const float4* xb = (const float4*)xg;
    const long base = row0 * (D_DIM / 4) + lane;  // float4 index, chunk j advances by 64
    float4 xv[4];
    if (row0 < nrows) {
        #pragma unroll
        for (int j = 0; j < 4; ++j) xv[j] = xb[base + j * 64];
    }

    for (int r = 0; r < ROWS_PER_WAVE; ++r) {
        const long row = row0 + r;
        if (row >= nrows) break;

        float4 xn[4];
        const bool pf = (r + 1 < ROWS_PER_WAVE) && (row + 1 < nrows);
        if (pf) {
            #pragma unroll
            for (int j = 0; j < 4; ++j) xn[j] = xb[base + (long)(r + 1) * 256 + j * 64];
        }

        // false dep on Vf each iteration: keep the 128 f32->f64 cvts inside the
        // loop (LICM hoisting them would materialize 256 VGPRs of doubles -> spill)
        #pragma unroll
        for (int n = 0; n < NLEV; ++n) {
            #pragma unroll
            for (int j = 0; j < 4; ++j) {
                asm volatile("" : "+v"(Vf[n][j].x), "+v"(Vf[n][j].y),
                                  "+v"(Vf[n][j].z), "+v"(Vf[n][j].w));
            }
        }

        double s = 0.0, sq = 0.0;
        double acc[NLEV];
        #pragma unroll
        for (int n = 0; n < NLEV; ++n) acc[n] = 0.0;

        #pragma unroll
        for (int j = 0; j < 4; ++j) {
            const double x0 = (double)xv[j].x;
            const double x1 = (double)xv[j].y;
            const double x2 = (double)xv[j].z;
            const double x3 = (double)xv[j].w;
            s += ((x0 + x1) + (x2 + x3));
            sq = fma(x0, x0, sq); sq = fma(x1, x1, sq);
            sq = fma(x2, x2, sq); sq = fma(x3, x3, sq);
            #pragma unroll
            for (int n = 0; n < NLEV; ++n) {
                acc[n] = fma(x0, (double)Vf[n][j].x, acc[n]);
                acc[n] = fma(x1, (double)Vf[n][j].y, acc[n]);
                acc[n] = fma(x2, (double)Vf[n][j].z, acc[n]);
                acc[n] = fma(x3, (double)Vf[n][j].w, acc[n]);
            }
        }

        // single combined butterfly: s, sq, 8 dot partials
        #pragma unroll
        for (int off = 32; off >= 1; off >>= 1) {
            s  += __shfl_xor(s, off, 64);
            sq += __shfl_xor(sq, off, 64);
            #pragma unroll
            for (int n = 0; n < NLEV; ++n)
                acc[n] += __shfl_xor(acc[n], off, 64);
        }

        // lane l selects S_(l&7)
        double a0 = (lane & 4) ? acc[4] : acc[0];
        double a1 = (lane & 4) ? acc[5] : acc[1];
        double a2 = (lane & 4) ? acc[6] : acc[2];
        double a3 = (lane & 4) ? acc[7] : acc[3];
        double b0 = (lane & 2) ? a2 : a0;
        double b1 = (lane & 2) ? a3 : a1;
        const double Ssel = (lane & 1) ? b1 : b0;

        if (lane < NLEV) {
            const double mean = s * (1.0 / 1024.0);
            const double var  = sq * (1.0 / 1024.0) - mean * mean;
            const double rstd = 1.0 / sqrt(var + 1e-5);
            // z_n = rstd*(S_n - mean*C1_n) + C0_n  ==  sum(((x-mean)*rstd*g + b) * W_n)
            const double z = rstd * (Ssel - mean * C1sel) + C0sel;
            const double half_l = 8.0 * (1.0 - 1e-3) / 2.0;  // constant-folded exactly as python
            const double bounded = half_l * tanh(z);
            outg[row * NLEV + lane] = (float)rint(bounded);   // round-half-even, matches np.round
        }

        if (pf) {
            #pragma unroll
            for (int j = 0; j < 4; ++j) xv[j] = xn[j];
        }
    }
}

extern "C" void kernel_launch(void* const* d_in, const int* in_sizes, int n_in,
                              void* d_out, int out_size, void* d_ws, size_t ws_size,
                              hipStream_t stream) {
    (void)n_in; (void)d_ws; (void)ws_size; (void)out_size;
    const float* regrs = (const float*)d_in[0];
    const float* ln_w  = (const float*)d_in[1];
    const float* ln_b  = (const float*)d_in[2];
    const float* W     = (const float*)d_in[3];
    float* out = (float*)d_out;

    const int nrows = in_sizes[0] / D_DIM;  // B*S = 32768
    const int rows_per_block = WAVES_PER_BLOCK * ROWS_PER_WAVE;  // 32
    const int nblocks = (nrows + rows_per_block - 1) / rows_per_block;  // 1024

    fsq_kernel<<<nblocks, 256, 0, stream>>>(regrs, ln_w, ln_b, W, out, nrows);
}

// Round 2
// 263.580 us; speedup vs baseline: 1.0206x; 1.0206x over previous
//
#include <hip/hip_runtime.h>
#include <math.h>

#define D_DIM 1024
#define NLEV 8
#define WAVES_PER_BLOCK 4
#define ROWS_PER_WAVE 8
// worst-case fp32 path error on `bounded` is ~2.5e-4 (gamma bound over the
// 22-op summation, ||x||<=32, ||g*W||<=1.1, + rstd & tanhf ulp). Flag at 2e-3
// = 8x margin. Expected flagged rows ~= 262144 outputs * ~1.0/unit boundary
// density * 4e-3 window ~= 1000 rows -> phase 2 is negligible.
#define FLAG_EPS 2.0e-3f

// ---------------- phase 1: fp32 fast path ----------------
__global__ __launch_bounds__(256, 2) void fsq_fp32_kernel(
    const float* __restrict__ xg,
    const float* __restrict__ gg,
    const float* __restrict__ bg,
    const float* __restrict__ Wg,
    float* __restrict__ outg,
    unsigned int* __restrict__ wl,   // wl[0]=counter, wl[16..] = row indices
    int wl_cap,
    int nrows)
{
    const int tid  = (int)threadIdx.x;
    const int lane = tid & 63;
    const int wv   = tid >> 6;
    const long wave_global = (long)blockIdx.x * WAVES_PER_BLOCK + wv;
    const long row0 = wave_global * ROWS_PER_WAVE;

    // V = g*W resident in fp32 registers (128 VGPRs), reused across 8 rows.
    // lane owns columns {j*256 + lane*4 .. +3}, j=0..3 (coalesced float4).
    float4 Vf[NLEV][4];
    float pc1[NLEV], pc0[NLEV];
    #pragma unroll
    for (int n = 0; n < NLEV; ++n) { pc1[n] = 0.0f; pc0[n] = 0.0f; }

    #pragma unroll
    for (int j = 0; j < 4; ++j) {
        const int col = j * 256 + lane * 4;
        const float4 g4 = *(const float4*)(gg + col);
        const float4 b4 = *(const float4*)(bg + col);
        #pragma unroll
        for (int n = 0; n < NLEV; ++n) {
            const float4 w4 = *(const float4*)(Wg + n * D_DIM + col);
            float4 v;
            v.x = g4.x * w4.x; v.y = g4.y * w4.y;
            v.z = g4.z * w4.z; v.w = g4.w * w4.w;
            Vf[n][j] = v;
            pc1[n] += ((v.x + v.y) + (v.z + v.w));
            pc0[n] += ((b4.x * w4.x + b4.y * w4.y) + (b4.z * w4.z + b4.w * w4.w));
        }
    }
    #pragma unroll
    for (int off = 32; off >= 1; off >>= 1) {
        #pragma unroll
        for (int n = 0; n < NLEV; ++n) {
            pc1[n] += __shfl_xor(pc1[n], off, 64);
            pc0[n] += __shfl_xor(pc0[n], off, 64);
        }
    }
    // lane l keeps C*(l&7): static select tree
    float su0, su1, su2, su3, sv0, sv1;
    su0 = (lane & 4) ? pc1[4] : pc1[0];
    su1 = (lane & 4) ? pc1[5] : pc1[1];
    su2 = (lane & 4) ? pc1[6] : pc1[2];
    su3 = (lane & 4) ? pc1[7] : pc1[3];
    sv0 = (lane & 2) ? su2 : su0;
    sv1 = (lane & 2) ? su3 : su1;
    const float C1sel = (lane & 1) ? sv1 : sv0;
    su0 = (lane & 4) ? pc0[4] : pc0[0];
    su1 = (lane & 4) ? pc0[5] : pc0[1];
    su2 = (lane & 4) ? pc0[6] : pc0[2];
    su3 = (lane & 4) ? pc0[7] : pc0[3];
    sv0 = (lane & 2) ? su2 : su0;
    sv1 = (lane & 2) ? su3 : su1;
    const float C0sel = (lane & 1) ? sv1 : sv0;

    const float4* xb = (const float4*)xg;
    const long base = row0 * (D_DIM / 4) + lane;
    float4 xv[4];
    if (row0 < nrows) {
        #pragma unroll
        for (int j = 0; j < 4; ++j) xv[j] = xb[base + j * 64];
    }

    for (int r = 0; r < ROWS_PER_WAVE; ++r) {
        const long row = row0 + r;
        if (row >= nrows) break;

        float4 xn[4];
        const bool pf = (r + 1 < ROWS_PER_WAVE) && (row + 1 < nrows);
        if (pf) {
            #pragma unroll
            for (int j = 0; j < 4; ++j) xn[j] = xb[base + (long)(r + 1) * 256 + j * 64];
        }

        float s = 0.0f, sq = 0.0f;
        float acc[NLEV];
        #pragma unroll
        for (int n = 0; n < NLEV; ++n) acc[n] = 0.0f;

        #pragma unroll
        for (int j = 0; j < 4; ++j) {
            const float x0 = xv[j].x, x1 = xv[j].y, x2 = xv[j].z, x3 = xv[j].w;
            s += ((x0 + x1) + (x2 + x3));
            sq = fmaf(x0, x0, sq); sq = fmaf(x1, x1, sq);
            sq = fmaf(x2, x2, sq); sq = fmaf(x3, x3, sq);
            #pragma unroll
            for (int n = 0; n < NLEV; ++n) {
                acc[n] = fmaf(x0, Vf[n][j].x, acc[n]);
                acc[n] = fmaf(x1, Vf[n][j].y, acc[n]);
                acc[n] = fmaf(x2, Vf[n][j].z, acc[n]);
                acc[n] = fmaf(x3, Vf[n][j].w, acc[n]);
            }
        }

        #pragma unroll
        for (int off = 32; off >= 1; off >>= 1) {
            s  += __shfl_xor(s, off, 64);
            sq += __shfl_xor(sq, off, 64);
            #pragma unroll
            for (int n = 0; n < NLEV; ++n)
                acc[n] += __shfl_xor(acc[n], off, 64);
        }

        float a0 = (lane & 4) ? acc[4] : acc[0];
        float a1 = (lane & 4) ? acc[5] : acc[1];
        float a2 = (lane & 4) ? acc[6] : acc[2];
        float a3 = (lane & 4) ? acc[7] : acc[3];
        float b0 = (lane & 2) ? a2 : a0;
        float b1 = (lane & 2) ? a3 : a1;
        const float Ssel = (lane & 1) ? b1 : b0;

        bool flag = false;
        if (lane < NLEV) {
            const float mean = s * (1.0f / 1024.0f);
            const float var  = sq * (1.0f / 1024.0f) - mean * mean;
            const float rstd = 1.0f / sqrtf(var + 1e-5f);
            const float z = rstd * (Ssel - mean * C1sel) + C0sel;
            const float bounded = 3.996f * tanhf(z);
            const float rr = rintf(bounded);
            outg[row * NLEV + lane] = rr;
            flag = (0.5f - fabsf(bounded - rr)) < FLAG_EPS;
        }
        const unsigned long long bal = __ballot(flag);
        if (lane == 0 && bal != 0ULL) {
            const unsigned idx = atomicAdd(wl, 1u);
            if (idx < (unsigned)wl_cap) wl[16 + idx] = (unsigned)row;
        }

        if (pf) {
            #pragma unroll
            for (int j = 0; j < 4; ++j) xv[j] = xn[j];
        }
    }
}

// ---------------- phase 2: fp64 repair of flagged rows ----------------
__global__ __launch_bounds__(256, 2) void fsq_fp64_fix(
    const float* __restrict__ xg,
    const float* __restrict__ gg,
    const float* __restrict__ bg,
    const float* __restrict__ Wg,
    float* __restrict__ outg,
    const unsigned int* __restrict__ wl,
    int wl_cap)
{
    const int tid  = (int)threadIdx.x;
    const int lane = tid & 63;
    const int wv   = tid >> 6;
    const unsigned wave   = blockIdx.x * WAVES_PER_BLOCK + wv;
    const unsigned nwaves = gridDim.x * WAVES_PER_BLOCK;

    unsigned cnt = wl[0];
    if (cnt > (unsigned)wl_cap) cnt = (unsigned)wl_cap;

    for (unsigned it = wave; it < cnt; it += nwaves) {
        const long row = (long)wl[16 + it];

        double s = 0.0, sq = 0.0;
        double acc[NLEV], c1[NLEV], c0[NLEV];
        #pragma unroll
        for (int n = 0; n < NLEV; ++n) { acc[n] = 0.0; c1[n] = 0.0; c0[n] = 0.0; }

        const float4* xb4 = (const float4*)(xg + row * D_DIM);
        #pragma unroll
        for (int j = 0; j < 4; ++j) {
            const int col = j * 256 + lane * 4;
            const float4 x4 = xb4[j * 64 + lane];
            const float4 g4 = *(const float4*)(gg + col);
            const float4 b4 = *(const float4*)(bg + col);
            const double x0 = (double)x4.x, x1 = (double)x4.y;
            const double x2 = (double)x4.z, x3 = (double)x4.w;
            s += ((x0 + x1) + (x2 + x3));
            sq = fma(x0, x0, sq); sq = fma(x1, x1, sq);
            sq = fma(x2, x2, sq); sq = fma(x3, x3, sq);
            #pragma unroll
            for (int n = 0; n < NLEV; ++n) {
                const float4 w4 = *(const float4*)(Wg + n * D_DIM + col);
                const double v0 = (double)g4.x * (double)w4.x;
                const double v1 = (double)g4.y * (double)w4.y;
                const double v2 = (double)g4.z * (double)w4.z;
                const double v3 = (double)g4.w * (double)w4.w;
                acc[n] = fma(x0, v0, acc[n]);
                acc[n] = fma(x1, v1, acc[n]);
                acc[n] = fma(x2, v2, acc[n]);
                acc[n] = fma(x3, v3, acc[n]);
                c1[n] += ((v0 + v1) + (v2 + v3));
                c0[n] += (((double)b4.x * (double)w4.x + (double)b4.y * (double)w4.y)
                        + ((double)b4.z * (double)w4.z + (double)b4.w * (double)w4.w));
            }
        }

        #pragma unroll
        for (int off = 32; off >= 1; off >>= 1) {
            s  += __shfl_xor(s, off, 64);
            sq += __shfl_xor(sq, off, 64);
            #pragma unroll
            for (int n = 0; n < NLEV; ++n) {
                acc[n] += __shfl_xor(acc[n], off, 64);
                c1[n]  += __shfl_xor(c1[n], off, 64);
                c0[n]  += __shfl_xor(c0[n], off, 64);
            }
        }

        if (lane < NLEV) {
            double a0 = (lane & 4) ? acc[4] : acc[0];
            double a1 = (lane & 4) ? acc[5] : acc[1];
            double a2 = (lane & 4) ? acc[6] : acc[2];
            double a3 = (lane & 4) ? acc[7] : acc[3];
            double b0 = (lane & 2) ? a2 : a0;
            double b1 = (lane & 2) ? a3 : a1;
            const double Ssel = (lane & 1) ? b1 : b0;
            a0 = (lane & 4) ? c1[4] : c1[0];
            a1 = (lane & 4) ? c1[5] : c1[1];
            a2 = (lane & 4) ? c1[6] : c1[2];
            a3 = (lane & 4) ? c1[7] : c1[3];
            b0 = (lane & 2) ? a2 : a0;
            b1 = (lane & 2) ? a3 : a1;
            const double C1sel = (lane & 1) ? b1 : b0;
            a0 = (lane & 4) ? c0[4] : c0[0];
            a1 = (lane & 4) ? c0[5] : c0[1];
            a2 = (lane & 4) ? c0[6] : c0[2];
            a3 = (lane & 4) ? c0[7] : c0[3];
            b0 = (lane & 2) ? a2 : a0;
            b1 = (lane & 2) ? a3 : a1;
            const double C0sel = (lane & 1) ? b1 : b0;

            const double mean = s * (1.0 / 1024.0);
            const double var  = sq * (1.0 / 1024.0) - mean * mean;
            const double rstd = 1.0 / sqrt(var + 1e-5);
            const double z = rstd * (Ssel - mean * C1sel) + C0sel;
            const double bounded = (8.0 * (1.0 - 1e-3) / 2.0) * tanh(z);
            outg[row * NLEV + lane] = (float)rint(bounded);
        }
    }
}

extern "C" void kernel_launch(void* const* d_in, const int* in_sizes, int n_in,
                              void* d_out, int out_size, void* d_ws, size_t ws_size,
                              hipStream_t stream) {
    (void)n_in; (void)out_size;
    const float* regrs = (const float*)d_in[0];
    const float* ln_w  = (const float*)d_in[1];
    const float* ln_b  = (const float*)d_in[2];
    const float* W     = (const float*)d_in[3];
    float* out = (float*)d_out;

    const int nrows = in_sizes[0] / D_DIM;  // 32768
    const int rows_per_block = WAVES_PER_BLOCK * ROWS_PER_WAVE;  // 32
    const int nblocks = (nrows + rows_per_block - 1) / rows_per_block;  // 1024

    unsigned int* wl = (unsigned int*)d_ws;
    long cap_l = ((long)(ws_size / 4)) - 16;
    if (cap_l < 0) cap_l = 0;
    if (cap_l > nrows) cap_l = nrows;
    const int wl_cap = (int)cap_l;

    // zero the worklist counter (d_ws is poisoned 0xAA before every call)
    hipMemsetAsync(d_ws, 0, 64, stream);
    fsq_fp32_kernel<<<nblocks, 256, 0, stream>>>(regrs, ln_w, ln_b, W, out,
                                                 wl, wl_cap, nrows);
    fsq_fp64_fix<<<128, 256, 0, stream>>>(regrs, ln_w, ln_b, W, out, wl, wl_cap);
}